// Round 6
// baseline (334.126 us; speedup 1.0000x reference)
//
#include <hip/hip_runtime.h>

typedef short bf16x8_t __attribute__((ext_vector_type(8)));
typedef float f32x4_t __attribute__((ext_vector_type(4)));

#define NTOK 577
#define QPAD 640   // q/k row padding; rows/cols >= 577 are zero
#define MPAD 608   // m range iterated (19*32)
#define NSTEP 19

__device__ __forceinline__ unsigned short f2bf(float f) {  // RNE
  unsigned u = __builtin_bit_cast(unsigned, f);
  u += 0x7FFFu + ((u >> 16) & 1u);
  return (unsigned short)(u >> 16);
}
__device__ __forceinline__ float headw(const float* wts, int h) {
  float w0 = wts[0], w1 = wts[1], w2 = wts[2];
  return (h < 8) ? (w0 + w1 + w2) : ((h < 10) ? (w1 + w2) : w2);
}
__device__ __forceinline__ unsigned rangemask(int lo, int hi) {
  lo = lo < 0 ? 0 : lo; hi = hi > 32 ? 32 : hi;
  if (hi <= lo) return 0u;
  unsigned mh = (hi >= 32) ? 0xFFFFFFFFu : ((1u << hi) - 1u);
  unsigned ml = (1u << lo) - 1u;
  return mh & ~ml;
}

// ---------------- prepass: one pass over x -> q*(w^2/8), k, v^T (all bf16) ----------------
extern "C" __global__ __launch_bounds__(256) void prep_x(
    const float* __restrict__ x, const float* __restrict__ wts,
    unsigned short* __restrict__ qbf, unsigned short* __restrict__ kbf,
    unsigned short* __restrict__ vbf) {
  __shared__ unsigned short t_s[64][72];
  const int tid = threadIdx.x;
  const int n0 = blockIdx.x * 64, h = blockIdx.y, b = blockIdx.z;
  const float w = headw(wts, h);
  const float qs = w * w * 0.125f;
  const float* xb = x + (size_t)(b * NTOK) * 2304 + h * 64;
  unsigned short* qo = qbf + ((size_t)(b * 12 + h)) * QPAD * 64;
  unsigned short* ko = kbf + ((size_t)(b * 12 + h)) * QPAD * 64;
  for (int p = 0; p < 4; ++p) {
    int idx = p * 256 + tid;
    int row = idx >> 4, c4 = idx & 15;
    int n = n0 + row;
    float4 vq = {0,0,0,0}, vk = {0,0,0,0}, vv = {0,0,0,0};
    if (n < NTOK) {
      const float* rp = xb + (size_t)n * 2304 + c4 * 4;
      vq = *(const float4*)rp;
      vk = *(const float4*)(rp + 768);
      vv = *(const float4*)(rp + 1536);
    }
    ushort4 oq, ok;
    oq.x = f2bf(vq.x * qs); oq.y = f2bf(vq.y * qs); oq.z = f2bf(vq.z * qs); oq.w = f2bf(vq.w * qs);
    ok.x = f2bf(vk.x); ok.y = f2bf(vk.y); ok.z = f2bf(vk.z); ok.w = f2bf(vk.w);
    *(ushort4*)(qo + (size_t)(n0 + row) * 64 + c4 * 4) = oq;
    *(ushort4*)(ko + (size_t)(n0 + row) * 64 + c4 * 4) = ok;
    t_s[c4 * 4 + 0][row] = f2bf(vv.x);
    t_s[c4 * 4 + 1][row] = f2bf(vv.y);
    t_s[c4 * 4 + 2][row] = f2bf(vv.z);
    t_s[c4 * 4 + 3][row] = f2bf(vv.w);
  }
  __syncthreads();
  for (int p = 0; p < 2; ++p) {
    int c = p * 256 + tid;
    int d = c >> 3, n8 = c & 7;
    bf16x8_t val = *(const bf16x8_t*)&t_s[d][n8 * 8];
    *(bf16x8_t*)(vbf + ((size_t)(b * 12 + h) * 64 + d) * QPAD + n0 + n8 * 8) = val;
  }
}

// ---------------- prepass: tables ----------------
extern "C" __global__ __launch_bounds__(256) void prep_tab(
    const float* __restrict__ wts,
    const float* __restrict__ tkv, const float* __restrict__ tkh,
    const float* __restrict__ tvv, const float* __restrict__ tvh,
    unsigned short* __restrict__ tkb, unsigned short* __restrict__ tvb) {
  int tid = threadIdx.x, bx = blockIdx.x;
  if (bx < 48) {
    int cid = bx * 256 + tid;
    int d4 = cid & 15, t = (cid >> 4) & 31, tb = (cid >> 9) & 1, h = cid >> 10;
    float s = 1.f / headw(wts, h);
    const float* src = tb ? tkh : tkv;
    float4 v = {0,0,0,0};
    if (t < 30) v = *(const float4*)(src + t * 64 + d4 * 4);
    ushort4 o;
    o.x = f2bf(v.x * s); o.y = f2bf(v.y * s); o.z = f2bf(v.z * s); o.w = f2bf(v.w * s);
    *(ushort4*)(tkb + (((size_t)(h * 2 + tb)) * 32 + t) * 64 + d4 * 4) = o;
  } else {
    for (int i = 0; i < 16; ++i) {
      int id = tid * 16 + i;              // 4096 = 2*64*32, t fastest
      int t = id & 31, d = (id >> 5) & 63, tb = id >> 11;
      const float* src = tb ? tvh : tvv;
      tvb[id] = (t < 30) ? f2bf(src[t * 64 + d]) : (unsigned short)0;
    }
  }
}

// ---------------- main kernel: 64 n-rows x full m per block; K=128 augmented S ----------------
struct __align__(16) SMem {
  unsigned gmask_s[2][NSTEP][25];      // 3800 B
  float l_s[64];                       // 256 B
  union __align__(16) U {              // 28160 B
    struct { float qv_t[2][64][30]; float qg[2][64][25]; } pro;
    struct {
      unsigned short k_s[2][32][72];   // double-buffered k
      unsigned short v_sT[2][64][40];  // double-buffered v^T
      unsigned short P_s[64][40];
    } loop;
    struct { float sv_f[2][64][30]; } epi;
  } u;
};  // 32224 B -> 5 blocks/CU

extern "C" __global__ __launch_bounds__(256, 5) void hma_kernel(
    const unsigned short* __restrict__ qbf, const unsigned short* __restrict__ kbf,
    const unsigned short* __restrict__ vbf, const unsigned short* __restrict__ tkb,
    const unsigned short* __restrict__ tvb, const float* __restrict__ wts,
    float* __restrict__ out) {
  __shared__ SMem sm;
  const int tid = threadIdx.x;
  const int wave = tid >> 6, lane = tid & 63, quad = lane >> 4, l15 = lane & 15;
  const int rg = wave & 1;      // n-half (32 rows)
  const int cg = wave >> 1;     // m-half / d-half / table id
  const int tb_w = cg;
  const int n0 = blockIdx.x * 64;
  const int h = blockIdx.y, b = blockIdx.z;
  const float w = headw(wts, h);

  const unsigned short* qb = qbf + ((size_t)(b * 12 + h)) * QPAD * 64;
  const unsigned short* kb = kbf + ((size_t)(b * 12 + h)) * QPAD * 64;
  const unsigned short* vb = vbf + ((size_t)(b * 12 + h)) * 64 * QPAD;

  // k/v staging registers: tile 0 loads issued first
  const int krow = tid >> 3, kch = tid & 7;
  const int vrow = tid >> 2, vch = tid & 3;
  const unsigned short* kptr = kb + (size_t)krow * 64 + kch * 8;
  const unsigned short* vptr = vb + (size_t)vrow * QPAD + vch * 8;
  bf16x8_t kreg = *(const bf16x8_t*)kptr;
  bf16x8_t vreg = *(const bf16x8_t*)vptr;

  // q fragments from global (pre-scaled bf16)
  bf16x8_t qa[2][2];
  for (int sub = 0; sub < 2; ++sub)
    for (int kk = 0; kk < 2; ++kk)
      qa[sub][kk] = *(const bf16x8_t*)(qb + (size_t)(n0 + rg * 32 + sub * 16 + l15) * 64 + kk * 32 + quad * 8);

  // gmask build
  for (int p = tid; p < 2 * NSTEP * 25; p += 256) {
    int tb = p / (NSTEP * 25), r2 = p % (NSTEP * 25), step = r2 / 25, g = r2 % 25;
    int m0 = step * 32;
    unsigned mask;
    if (g == 24) {
      mask = rangemask(NTOK - m0, MPAD - m0);
      if (step == 0) mask |= 1u;
    } else if (tb == 0) {
      mask = rangemask(24 * g + 1 - m0, 24 * g + 25 - m0);
    } else {
      mask = 0u;
      int j0 = (g + 1 - m0) % 24; if (j0 < 0) j0 += 24;
      for (int j = j0; j < 32; j += 24) {
        int m = m0 + j;
        if (m >= 1 && m < NTOK) mask |= (1u << j);
      }
    }
    sm.gmask_s[tb][step][g] = mask;
  }

  // qv = q_hat . tk^T  (B-frags from global; wave -> table tb_w, n-half rg)
  {
    const unsigned short* tkp = tkb + ((size_t)(h * 2 + tb_w)) * 32 * 64;
    for (int tt = 0; tt < 2; ++tt) {
      for (int sub = 0; sub < 2; ++sub) {
        f32x4_t acc = {0.f, 0.f, 0.f, 0.f};
        for (int kk = 0; kk < 2; ++kk) {
          bf16x8_t bb = *(const bf16x8_t*)(tkp + (size_t)(tt * 16 + l15) * 64 + kk * 32 + quad * 8);
          acc = __builtin_amdgcn_mfma_f32_16x16x32_bf16(qa[sub][kk], bb, acc, 0, 0, 0);
        }
        int t = tt * 16 + l15;
        if (t < 30)
          for (int r = 0; r < 4; ++r)
            sm.u.pro.qv_t[tb_w][rg * 32 + sub * 16 + quad * 4 + r][t] = acc[r];
      }
    }
  }
  __syncthreads();
  // pre-scatter rel-k bias by group: qg[tb][n][g] = qv[tb][n][t(n,g)]
  for (int p = tid; p < 2 * 64 * 25; p += 256) {
    int tb = p / 1600, r2 = p % 1600, n = r2 / 25, g = r2 % 25;
    int n_g = n0 + n;
    int t;
    if (n_g == 0 || n_g >= NTOK || g == 24) t = 0;
    else {
      int base = tb ? ((n_g - 1) % 24) : ((n_g - 1) / 24);
      int dq = g - base; dq = dq < -14 ? -14 : (dq > 14 ? 14 : dq);
      t = dq + 15;
    }
    sm.u.pro.qg[tb][n][g] = sm.u.pro.qv_t[tb][n][t];
  }
  __syncthreads();
  // A-aug bias fragments (registers, bf16)
  bf16x8_t qga[2][2];
  for (int sub = 0; sub < 2; ++sub)
    for (int tb = 0; tb < 2; ++tb) {
      int n_loc = rg * 32 + sub * 16 + l15;
      for (int j = 0; j < 8; ++j) {
        int g = quad * 8 + j;
        float f = (g < 25) ? sm.u.pro.qg[tb][n_loc][g] : 0.f;
        qga[sub][tb][j] = (short)f2bf(f);
      }
    }
  __syncthreads();   // qga reads done; union region free for loop staging
  // stage tile 0 into buf0, prefetch tile 1
  *(bf16x8_t*)&sm.u.loop.k_s[0][krow][kch * 8] = kreg;
  *(bf16x8_t*)&sm.u.loop.v_sT[0][vrow][vch * 8] = vreg;
  kreg = *(const bf16x8_t*)(kptr + (size_t)32 * 64);
  vreg = *(const bf16x8_t*)(vptr + 32);
  __syncthreads();

  // per-thread m-group trackers (lane m = cg*16+l15)
  const int m_loc = cg * 16 + l15;
  int rmv, cmv;
  if (m_loc == 0) { rmv = 0; cmv = -1; }
  else { rmv = (m_loc - 1) / 24; cmv = (m_loc - 1) - rmv * 24; }
  const bool cls_lane = (m_loc == 0);

  f32x4_t oacc[2][2] = {{{0,0,0,0},{0,0,0,0}},{{0,0,0,0},{0,0,0,0}}};
  f32x4_t rsacc[2][2] = {{{0,0,0,0},{0,0,0,0}},{{0,0,0,0},{0,0,0,0}}};

  int cur = 0;
  for (int step = 0; step < NSTEP; ++step) {
    const int m0 = step * 32;
    const int nxt = cur ^ 1;
    // ---- phase A ----
    int ur = rmv, uc = cmv;
    if (cls_lane && step == 0) { ur = 24; uc = 24; }
    unsigned tr = (unsigned)ur - (unsigned)(quad * 8);
    unsigned tc = (unsigned)uc - (unsigned)(quad * 8);
    union { unsigned uu[4]; bf16x8_t v; } gr, gc;
#pragma unroll
    for (int i = 0; i < 4; ++i) {
      gr.uu[i] = ((tr >> 1) == (unsigned)i) ? (0x3F80u << (16 * (tr & 1))) : 0u;
      gc.uu[i] = ((tc >> 1) == (unsigned)i) ? (0x3F80u << (16 * (tc & 1))) : 0u;
    }
    f32x4_t s[2] = {{0,0,0,0},{0,0,0,0}};
    {
      bf16x8_t kb0 = *(const bf16x8_t*)&sm.u.loop.k_s[cur][m_loc][quad * 8];
      bf16x8_t kb1 = *(const bf16x8_t*)&sm.u.loop.k_s[cur][m_loc][32 + quad * 8];
      for (int sub = 0; sub < 2; ++sub) {
        s[sub] = __builtin_amdgcn_mfma_f32_16x16x32_bf16(qa[sub][0], kb0, s[sub], 0, 0, 0);
        s[sub] = __builtin_amdgcn_mfma_f32_16x16x32_bf16(qa[sub][1], kb1, s[sub], 0, 0, 0);
        s[sub] = __builtin_amdgcn_mfma_f32_16x16x32_bf16(qga[sub][0], gr.v, s[sub], 0, 0, 0);
        s[sub] = __builtin_amdgcn_mfma_f32_16x16x32_bf16(qga[sub][1], gc.v, s[sub], 0, 0, 0);
      }
    }
    // stage tile step+1 -> buf nxt; prefetch tile step+2
    *(bf16x8_t*)&sm.u.loop.k_s[nxt][krow][kch * 8] = kreg;
    *(bf16x8_t*)&sm.u.loop.v_sT[nxt][vrow][vch * 8] = vreg;
    if (step < NSTEP - 2) {
      kreg = *(const bf16x8_t*)(kptr + (size_t)(m0 + 64) * 64);
      vreg = *(const bf16x8_t*)(vptr + (m0 + 64));
    }
    // exp -> P (bias included via MFMA)
    const bool mpad = (m0 + m_loc >= NTOK);
    for (int sub = 0; sub < 2; ++sub)
      for (int r = 0; r < 4; ++r) {
        int n_loc = rg * 32 + sub * 16 + quad * 4 + r;
        float p = __expf(s[sub][r]);
        if (mpad) p = 0.f;
        unsigned u = __builtin_bit_cast(unsigned, p);
        sm.u.loop.P_s[n_loc][m_loc] = (unsigned short)((u + 0x8000u) >> 16);
      }
    { int c = cmv + 8; int carry = (c >= 24); cmv = carry ? c - 24 : c; rmv += 1 + carry; }
    __syncthreads();   // P + staged(nxt) visible
    // ---- phase B ----
    bf16x8_t pa[2];
    for (int sub = 0; sub < 2; ++sub)
      pa[sub] = *(const bf16x8_t*)&sm.u.loop.P_s[rg * 32 + sub * 16 + l15][quad * 8];
    for (int ds = 0; ds < 2; ++ds) {
      bf16x8_t bb = *(const bf16x8_t*)&sm.u.loop.v_sT[cur][cg * 32 + ds * 16 + l15][quad * 8];
      for (int sub = 0; sub < 2; ++sub)
        oacc[sub][ds] = __builtin_amdgcn_mfma_f32_16x16x32_bf16(pa[sub], bb, oacc[sub][ds], 0, 0, 0);
    }
    for (int gt = 0; gt < 2; ++gt) {
      unsigned g = (unsigned)(gt * 16 + l15);
      unsigned mask = (g < 25) ? sm.gmask_s[tb_w][step][g] : 0u;
      unsigned bits = (mask >> (quad * 8)) & 0xFFu;
      unsigned y0 = ((bits & 0xFu) * 0x204081u) & 0x01010101u;
      unsigned y1 = ((bits >> 4) * 0x204081u) & 0x01010101u;
      unsigned p01 = y0 & 0x0101u, p23 = (y0 >> 16) & 0x0101u;
      unsigned p45 = y1 & 0x0101u, p67 = (y1 >> 16) & 0x0101u;
      union { unsigned uu[4]; bf16x8_t v; } gbu;
      gbu.uu[0] = ((p01 | (p01 << 8)) & 0x00010001u) * 0x3F80u;
      gbu.uu[1] = ((p23 | (p23 << 8)) & 0x00010001u) * 0x3F80u;
      gbu.uu[2] = ((p45 | (p45 << 8)) & 0x00010001u) * 0x3F80u;
      gbu.uu[3] = ((p67 | (p67 << 8)) & 0x00010001u) * 0x3F80u;
      for (int sub = 0; sub < 2; ++sub)
        rsacc[sub][gt] = __builtin_amdgcn_mfma_f32_16x16x32_bf16(pa[sub], gbu.v, rsacc[sub][gt], 0, 0, 0);
    }
    __syncthreads();   // phase-B reads done
    cur = nxt;
  }

  // ---- epilogue ----
  for (int e = tid; e < 2 * 64 * 30; e += 256) (&sm.u.epi.sv_f[0][0][0])[e] = 0.f;
  __syncthreads();
  for (int sub = 0; sub < 2; ++sub)
    for (int gt = 0; gt < 2; ++gt) {
      int g = gt * 16 + l15;
      if (g < 25) {
        for (int r = 0; r < 4; ++r) {
          int n_loc = rg * 32 + sub * 16 + quad * 4 + r;
          int n_g = n0 + n_loc;
          int t;
          if (n_g == 0 || n_g >= NTOK || g == 24) t = 0;
          else {
            int base = tb_w ? ((n_g - 1) % 24) : ((n_g - 1) / 24);
            int dq = g - base; dq = dq < -14 ? -14 : (dq > 14 ? 14 : dq);
            t = dq + 15;
          }
          atomicAdd(&sm.u.epi.sv_f[tb_w][n_loc][t], rsacc[sub][gt][r]);
        }
      }
    }
  __syncthreads();
  if (tid < 64) {
    float l = 0.f;
    for (int t = 0; t < 30; ++t) l += sm.u.epi.sv_f[0][tid][t];
    sm.l_s[tid] = l;
  }
  for (int sub = 0; sub < 2; ++sub)
    for (int ds = 0; ds < 2; ++ds)
      for (int r = 0; r < 4; ++r) oacc[sub][ds][r] *= w;   // scale P.V part only
  // O += sv . tv^T
  for (int tb = 0; tb < 2; ++tb) {
    bf16x8_t av[2];
    for (int sub = 0; sub < 2; ++sub) {
      int n_loc = rg * 32 + sub * 16 + l15;
      for (int j = 0; j < 8; ++j) {
        int t = quad * 8 + j;
        float f = (t < 30) ? sm.u.epi.sv_f[tb][n_loc][t] : 0.f;
        unsigned u = __builtin_bit_cast(unsigned, f);
        av[sub][j] = (short)((u + 0x8000u) >> 16);
      }
    }
    for (int ds = 0; ds < 2; ++ds) {
      bf16x8_t bb = *(const bf16x8_t*)(tvb + ((size_t)(tb * 64 + cg * 32 + ds * 16 + l15)) * 32 + quad * 8);
      for (int sub = 0; sub < 2; ++sub)
        oacc[sub][ds] = __builtin_amdgcn_mfma_f32_16x16x32_bf16(av[sub], bb, oacc[sub][ds], 0, 0, 0);
    }
  }
  __syncthreads();   // l_s ready
  float* ob = out + (size_t)b * NTOK * 768 + h * 64;
  for (int sub = 0; sub < 2; ++sub)
    for (int r = 0; r < 4; ++r) {
      int n_loc = rg * 32 + sub * 16 + quad * 4 + r;
      int n_g = n0 + n_loc;
      if (n_g < NTOK) {
        float inv = 1.f / sm.l_s[n_loc];
        for (int ds = 0; ds < 2; ++ds) {
          int d = cg * 32 + ds * 16 + l15;
          ob[(size_t)n_g * 768 + d] = oacc[sub][ds][r] * inv;
        }
      }
    }
}

extern "C" void kernel_launch(void* const* d_in, const int* in_sizes, int n_in,
                              void* d_out, int out_size, void* d_ws, size_t ws_size,
                              hipStream_t stream) {
  const float* x   = (const float*)d_in[0];
  const float* wts = (const float*)d_in[1];
  const float* tkv = (const float*)d_in[2];
  const float* tkh = (const float*)d_in[3];
  const float* tvv = (const float*)d_in[4];
  const float* tvh = (const float*)d_in[5];
  float* out = (float*)d_out;
  const int B = in_sizes[0] / (NTOK * 2304);

  unsigned short* ws = (unsigned short*)d_ws;
  size_t qkSz = (size_t)B * 12 * QPAD * 64;
  unsigned short* qbf = ws;
  unsigned short* kbf = ws + qkSz;
  unsigned short* vbf = ws + 2 * qkSz;
  unsigned short* tkb = vbf + qkSz;
  unsigned short* tvb = tkb + (size_t)12 * 2 * 32 * 64;

  prep_x<<<dim3(10, 12, B), 256, 0, stream>>>(x, wts, qbf, kbf, vbf);
  prep_tab<<<dim3(49, 1, 1), 256, 0, stream>>>(wts, tkv, tkh, tvv, tvh, tkb, tvb);
  hma_kernel<<<dim3(10, 12, B), 256, 0, stream>>>(qbf, kbf, vbf, tkb, tvb, wts, out);
}